// Round 4
// baseline (262.181 us; speedup 1.0000x reference)
//
#include <hip/hip_runtime.h>
#include <hip/hip_bf16.h>
#include <cstdint>

// Problem constants: B=8, T=1024, C=1024, H=16, D=64
// FLOPs: proj 51.5G (3x 8192x1024x1024), attn ~17G causal.
// All-bf16 MFMA pipeline; tolerance is bf16-floor (8.06e-2).
//
// R4 changes vs R3: single-barrier double-buffered K-loops.
//  Old shape (m97-style): stage -> waitcnt(0)+barrier -> compute  => every
//  iteration exposes full load latency (occupancy 21%, MfmaUtil 16%).
//  New shape: stage(kt+1 -> buf^1) issued BEFORE compute(buf); the barrier's
//  implicit vmcnt(0) drain lands AFTER ~400cyc of MFMA+ds_read => latency
//  hidden inside the block; one barrier/iter instead of two.
//  k_proj LDS 32->64KB (2 blocks/CU, fine: in-block pipelining replaces
//  cross-block overlap). k_attn K/V double-buffered (48KB, 3 blocks/CU).

typedef __attribute__((ext_vector_type(8))) short short8;   // 8 x bf16 (A/B frag)
typedef __attribute__((ext_vector_type(4))) short bfs4;     // 4 x bf16 packed
typedef __attribute__((ext_vector_type(4))) float f32x4;    // C/D frag

typedef const __attribute__((address_space(1))) void* gas1_t;
typedef __attribute__((address_space(3))) void* las3_t;

__device__ __forceinline__ void gl_lds16(const void* g, void* l) {
  // async global->LDS, 16B per lane; LDS dest = wave-uniform base + lane*16
  __builtin_amdgcn_global_load_lds((gas1_t)g, (las3_t)l, 16, 0, 0);
}

__device__ __forceinline__ unsigned short f2bf(float f) {
  union { float f; unsigned int u; } v; v.f = f;
  unsigned int u = v.u;
  return (unsigned short)((u + 0x7fffu + ((u >> 16) & 1u)) >> 16); // RNE
}

__device__ __forceinline__ unsigned int pk_bf16(float a, float b) {
  union { __hip_bfloat162 h; unsigned int u; } cv;
  cv.h = __float22bfloat162_rn(make_float2(a, b));   // v_cvt_pk_bf16_f32
  return cv.u;
}

// ---------------------------------------------------------------- convert x
__global__ __launch_bounds__(256) void k_convert_x(const float* __restrict__ x,
                                                   unsigned short* __restrict__ xb) {
  int g = blockIdx.x * 256 + threadIdx.x;      // 1M threads, 8 elems each
  const float4* xp = (const float4*)x + (size_t)g * 2;
  float4 a = xp[0], b = xp[1];
  short8 o;
  o[0] = (short)f2bf(a.x); o[1] = (short)f2bf(a.y);
  o[2] = (short)f2bf(a.z); o[3] = (short)f2bf(a.w);
  o[4] = (short)f2bf(b.x); o[5] = (short)f2bf(b.y);
  o[6] = (short)f2bf(b.z); o[7] = (short)f2bf(b.w);
  *(short8*)(xb + (size_t)g * 8) = o;
}

// ------------------------------------------------- convert + transpose W
// Wt[p][h][d][c] = W_p[h][c][d], bf16.
__global__ __launch_bounds__(256) void k_convert_w(const float* __restrict__ Wq,
                                                   const float* __restrict__ Wk,
                                                   const float* __restrict__ Wv,
                                                   unsigned short* __restrict__ Wt) {
  int g = blockIdx.x * 256 + threadIdx.x;      // 3*16*128*64 = 393216
  int d  = g & 63;
  int cb = (g >> 6) & 127;
  int h  = (g >> 13) & 15;
  int p  = g >> 17;
  const float* W = (p == 0) ? Wq : (p == 1) ? Wk : Wv;
  const float* src = W + ((size_t)h * 1024 + cb * 8) * 64 + d;
  short8 o;
#pragma unroll
  for (int j = 0; j < 8; ++j) o[j] = (short)f2bf(src[(size_t)j * 64]);
  *(short8*)(Wt + (((size_t)p * 16 + h) * 64 + d) * 1024 + cb * 8) = o;
}

// ---------------------------------------------------------------- QKV GEMM
// C[m][n] = sum_c A[m][c] * B[n][c]; A,B row-major [rows][1024] bf16.
// p=0: A=xb, B=Wt_q -> Qb[b][h][t][d];  p=1: -> Kb
// p=2: A=Wt_v, B=xb -> Vt[b][h][d][t]
// XCD swizzle: the 8 blocks sharing an xb tile get the same (bid&7) -> XCD.
// Pipelined: double-buffered LDS, one barrier per K-iteration.
__global__ __launch_bounds__(256) void k_proj(const unsigned short* __restrict__ xb,
                                              const unsigned short* __restrict__ Wt,
                                              unsigned short* __restrict__ Qb,
                                              unsigned short* __restrict__ Kb,
                                              unsigned short* __restrict__ Vt) {
  __shared__ alignas(16) unsigned short As[2][8192];   // 2 x 128x64 bf16, frag-major
  __shared__ alignas(16) unsigned short Bs[2][8192];
  const int p   = blockIdx.y;
  const int bx  = blockIdx.x;
  const int tid = threadIdx.x;
  const int lane = tid & 63, w = tid >> 6;
  const int ln = lane & 15, quad = lane >> 4;
  const int wm = w >> 1, wn = w & 1;

  const unsigned short* Abase;
  const unsigned short* Bbase;
  int m0, n0;
  const int c = bx & 7, j = bx >> 3;          // c = XCD id
  if (p < 2) {
    Abase = xb; Bbase = Wt + (size_t)p * 1048576;
    m0 = ((j >> 3) * 8 + c) * 128;            // xb m-tile pinned to XCD c
    n0 = (j & 7) * 128;
  } else {
    Abase = Wt + (size_t)2 * 1048576; Bbase = xb;
    n0 = ((j >> 3) * 8 + c) * 128;            // xb n-tile pinned to XCD c
    m0 = (j & 7) * 128;
  }

  // staging: 4 chunks x 256 threads x 16B each for A and B
  auto stage = [&](int kt, int buf) {
    const int c0 = kt * 64;
#pragma unroll
    for (int i = 0; i < 4; ++i) {
      int idx = i * 256 + tid;                 // chunk = ikk*512 + imt*64 + iq*16 + iln
      int iln = idx & 15, iq = (idx >> 4) & 3, imt = (idx >> 6) & 7, ikk = (idx >> 9) & 1;
      int row = imt * 16 + iln;
      int col = c0 + ikk * 32 + iq * 8;
      char* la = (char*)&As[buf][0] + (size_t)(i * 256 + (tid & ~63)) * 16;
      char* lb = (char*)&Bs[buf][0] + (size_t)(i * 256 + (tid & ~63)) * 16;
      gl_lds16(Abase + (size_t)(m0 + row) * 1024 + col, la);
      gl_lds16(Bbase + (size_t)(n0 + row) * 1024 + col, lb);
    }
  };

  f32x4 acc[4][4];
#pragma unroll
  for (int i = 0; i < 4; ++i)
#pragma unroll
    for (int jj = 0; jj < 4; ++jj) acc[i][jj] = (f32x4){0.f, 0.f, 0.f, 0.f};

  stage(0, 0);
  __syncthreads();                             // publishes buf0 (drains vmcnt)

  for (int kt = 0; kt < 16; ++kt) {
    const int cur = kt & 1;
    if (kt < 15) stage(kt + 1, cur ^ 1);       // async prefetch, in flight during compute

    short8 af[2][4], bfr[2][4];
#pragma unroll
    for (int kk = 0; kk < 2; ++kk)
#pragma unroll
      for (int t4 = 0; t4 < 4; ++t4) {
        af[kk][t4]  = *(const short8*)&As[cur][(size_t)((((kk * 8 + wm * 4 + t4) * 4 + quad) * 16 + ln)) * 8];
        bfr[kk][t4] = *(const short8*)&Bs[cur][(size_t)((((kk * 8 + wn * 4 + t4) * 4 + quad) * 16 + ln)) * 8];
      }
#pragma unroll
    for (int kk = 0; kk < 2; ++kk)
#pragma unroll
      for (int mt = 0; mt < 4; ++mt)
#pragma unroll
        for (int nt = 0; nt < 4; ++nt)
          acc[mt][nt] = __builtin_amdgcn_mfma_f32_16x16x32_bf16(
              af[kk][mt], bfr[kk][nt], acc[mt][nt], 0, 0, 0);

    __syncthreads();   // drains prefetch (after compute) + frees cur buffer
  }

  unsigned short* outp = (p == 0) ? Qb : (p == 1) ? Kb : Vt;
#pragma unroll
  for (int mt = 0; mt < 4; ++mt)
#pragma unroll
    for (int nt = 0; nt < 4; ++nt)
#pragma unroll
      for (int r = 0; r < 4; ++r) {
        int m = m0 + (wm * 4 + mt) * 16 + quad * 4 + r;
        int n = n0 + (wn * 4 + nt) * 16 + ln;
        size_t addr;
        if (p < 2) {
          // [b][h][t][d]: m = b*1024+t, n = h*64+d
          addr = ((size_t)(m >> 10) * 16 + (n >> 6)) * 65536 + (size_t)(m & 1023) * 64 + (n & 63);
        } else {
          // Vt [b][h][d][t]: m = h*64+d, n = b*1024+t
          addr = ((size_t)(n >> 10) * 1024 + m) * 1024 + (n & 1023);
        }
        outp[addr] = f2bf(acc[mt][nt][r]);
      }
}

// ----------------------------------------------------------- flash attention
// 1-D grid, 1024 blocks. bid&127 = bh -> XCD = bh%8: all q-blocks of one
// (b,h) share one XCD's L2. qb = 7-(bid>>7): heavy blocks first.
// Block = 128 queries (4 waves x 2 q-tiles of 16). 64 keys per iteration.
// St = K*Q^T (softmax rows per-lane); fixed-max softmax (M=16, shift-exact);
// O^T = V^T*P^T; P crosses C->B layout via per-wave LDS.
// Pipelined: K/V double-buffered, one barrier per iteration.
__global__ __launch_bounds__(256) void k_attn(const unsigned short* __restrict__ Qb,
                                              const unsigned short* __restrict__ Kb,
                                              const unsigned short* __restrict__ Vt,
                                              float* __restrict__ out) {
  __shared__ alignas(16) unsigned short Ks[2][4096];   // 64s x 64d frag-major
  __shared__ alignas(16) unsigned short Vs[2][4096];   // 64d x 64s frag-major
  __shared__ alignas(16) unsigned short Ps[8192];      // 4 waves x 2 qt x 16q x 64s
  const int bid = blockIdx.x;
  const int qb = 7 - (bid >> 7);
  const int bh = bid & 127;
  const int b = bh >> 4, h = bh & 15;
  const int tid = threadIdx.x, lane = tid & 63, w = tid >> 6;
  const int ln = lane & 15, quad = lane >> 4;

  auto stage = [&](int kt, int buf) {
    const int s0 = kt * 64;
#pragma unroll
    for (int i = 0; i < 2; ++i) {
      int idx = i * 256 + tid;               // chunk = it*128 + ikk*64 + iq*16 + iln
      int iln = idx & 15, iq = (idx >> 4) & 3, ikk = (idx >> 6) & 1, it = (idx >> 7) & 3;
      char* lk = (char*)&Ks[buf][0] + (size_t)(i * 256 + (tid & ~63)) * 16;
      char* lv = (char*)&Vs[buf][0] + (size_t)(i * 256 + (tid & ~63)) * 16;
      gl_lds16(Kb + ((size_t)bh * 1024 + s0 + it * 16 + iln) * 64 + ikk * 32 + iq * 8, lk);
      gl_lds16(Vt + ((size_t)bh * 64 + it * 16 + iln) * 1024 + s0 + ikk * 32 + iq * 8, lv);
    }
  };

  // Q B-frags for both q-tiles: lane n=q holds Q[q][kk*32+quad*8 .. +7]
  short8 qf[2][2];
#pragma unroll
  for (int qt = 0; qt < 2; ++qt) {
    const int q = qb * 128 + qt * 64 + w * 16 + ln;
#pragma unroll
    for (int kk = 0; kk < 2; ++kk)
      qf[qt][kk] = *(const short8*)(Qb + ((size_t)bh * 1024 + q) * 64 + kk * 32 + quad * 8);
  }

  f32x4 o[2][4];
#pragma unroll
  for (int qt = 0; qt < 2; ++qt)
#pragma unroll
    for (int dt = 0; dt < 4; ++dt) o[qt][dt] = (f32x4){0.f, 0.f, 0.f, 0.f};
  float l_i[2] = {0.f, 0.f};
  const float sc = 0.18033688011112042f;  // log2(e) / sqrt(64)
  const float FM = 16.0f;                 // fixed log2-domain max; |sc*st| << 16

  const int ktmax = 2 * qb + 1;
  stage(0, 0);
  __syncthreads();

  for (int kt = 0; kt <= ktmax; ++kt) {
    const int cur = kt & 1;
    const int s0 = kt * 64;
    if (kt < ktmax) stage(kt + 1, cur ^ 1);   // prefetch next K/V tile

    // QK phase: St[qt][s][q] = sum_d K[s][d] Q[q][d], kf shared across qt
    f32x4 st[2][4];
#pragma unroll
    for (int s = 0; s < 4; ++s) {
      st[0][s] = (f32x4){0.f, 0.f, 0.f, 0.f};
      st[1][s] = (f32x4){0.f, 0.f, 0.f, 0.f};
#pragma unroll
      for (int kk = 0; kk < 2; ++kk) {
        short8 kf = *(const short8*)&Ks[cur][(size_t)(((s * 2 + kk) * 4 + quad) * 16 + ln) * 8];
        st[0][s] = __builtin_amdgcn_mfma_f32_16x16x32_bf16(kf, qf[0][kk], st[0][s], 0, 0, 0);
        st[1][s] = __builtin_amdgcn_mfma_f32_16x16x32_bf16(kf, qf[1][kk], st[1][s], 0, 0, 0);
      }
    }

    // softmax (fixed max) + P->LDS, per qt
#pragma unroll
    for (int qt = 0; qt < 2; ++qt) {
      const int q = qb * 128 + qt * 64 + w * 16 + ln;
      const bool masked = (kt >= 2 * qb + qt);   // diag tile (or fully-beyond)
      float pv[4][4];
      float rs = 0.f;
#pragma unroll
      for (int s = 0; s < 4; ++s)
#pragma unroll
        for (int r = 0; r < 4; ++r) {
          float v = fmaf(st[qt][s][r], sc, -FM);
          if (masked) {
            int sidx = s0 + s * 16 + quad * 4 + r;
            if (sidx > q) v = -1.0e30f;
          }
          float e = __builtin_amdgcn_exp2f(v);
          pv[s][r] = e;
          rs += e;
        }
      rs += __shfl_xor(rs, 16);
      rs += __shfl_xor(rs, 32);
      l_i[qt] += rs;

      unsigned short* Pq = Ps + (w * 2 + qt) * 1024;
#pragma unroll
      for (int s = 0; s < 4; ++s) {
        union { bfs4 v; unsigned int u[2]; } pk;
        pk.u[0] = pk_bf16(pv[s][0], pv[s][1]);
        pk.u[1] = pk_bf16(pv[s][2], pv[s][3]);
        *(bfs4*)&Pq[(s * 2 + (quad >> 1)) * 128 + ln * 8 + (quad & 1) * 4] = pk.v;
      }
    }

    // PV phase: O^T += V^T * P^T, vf shared across qt
#pragma unroll
    for (int kk = 0; kk < 2; ++kk) {
      short8 pf0 = *(const short8*)&Ps[(size_t)(w * 2 + 0) * 1024 + (size_t)((kk * 4 + quad) * 16 + ln) * 8];
      short8 pf1 = *(const short8*)&Ps[(size_t)(w * 2 + 1) * 1024 + (size_t)((kk * 4 + quad) * 16 + ln) * 8];
#pragma unroll
      for (int dt = 0; dt < 4; ++dt) {
        short8 vf = *(const short8*)&Vs[cur][(size_t)(((dt * 2 + kk) * 4 + quad) * 16 + ln) * 8];
        o[0][dt] = __builtin_amdgcn_mfma_f32_16x16x32_bf16(vf, pf0, o[0][dt], 0, 0, 0);
        o[1][dt] = __builtin_amdgcn_mfma_f32_16x16x32_bf16(vf, pf1, o[1][dt], 0, 0, 0);
      }
    }

    __syncthreads();   // drains prefetch (after compute); frees cur K/V buffer
  }

#pragma unroll
  for (int qt = 0; qt < 2; ++qt) {
    const int q = qb * 128 + qt * 64 + w * 16 + ln;
    const float rl = 1.0f / l_i[qt];
#pragma unroll
    for (int dt = 0; dt < 4; ++dt) {
      float4 ov;
      ov.x = o[qt][dt][0] * rl; ov.y = o[qt][dt][1] * rl;
      ov.z = o[qt][dt][2] * rl; ov.w = o[qt][dt][3] * rl;
      *(float4*)(out + ((size_t)b * 1024 + q) * 1024 + h * 64 + dt * 16 + quad * 4) = ov;
    }
  }
}

// ---------------------------------------------------------------- launcher
extern "C" void kernel_launch(void* const* d_in, const int* in_sizes, int n_in,
                              void* d_out, int out_size, void* d_ws, size_t ws_size,
                              hipStream_t stream) {
  const float* x  = (const float*)d_in[0];
  const float* Wq = (const float*)d_in[1];
  const float* Wk = (const float*)d_in[2];
  const float* Wv = (const float*)d_in[3];
  float* out = (float*)d_out;

  unsigned short* ws = (unsigned short*)d_ws;
  unsigned short* xb = ws;                      // 8M bf16  (16 MB)
  unsigned short* Wt = ws + 8388608;            // 3M bf16  (6 MB), [p][h][d][c]
  unsigned short* Qb = ws + 11534336;           // 8M bf16  [b][h][t][d]
  unsigned short* Kb = ws + 19922944;           // 8M bf16  [b][h][t][d]
  unsigned short* Vt = ws + 28311552;           // 8M bf16  [b][h][d][t]
  // total 73,400,320 bytes of d_ws

  hipLaunchKernelGGL(k_convert_x, dim3(4096), dim3(256), 0, stream, x, xb);
  hipLaunchKernelGGL(k_convert_w, dim3(1536), dim3(256), 0, stream, Wq, Wk, Wv, Wt);
  hipLaunchKernelGGL(k_proj, dim3(512, 3), dim3(256), 0, stream, xb, Wt, Qb, Kb, Vt);
  hipLaunchKernelGGL(k_attn, dim3(1024), dim3(256), 0, stream, Qb, Kb, Vt, out);
}

// Round 5
// 232.129 us; speedup vs baseline: 1.1295x; 1.1295x over previous
//
#include <hip/hip_runtime.h>
#include <hip/hip_bf16.h>
#include <cstdint>

// Problem constants: B=8, T=1024, C=1024, H=16, D=64
// FLOPs: proj 51.5G (3x 8192x1024x1024), attn ~17G causal.
// All-bf16 MFMA pipeline; tolerance is bf16-floor (8.06e-2).
//
// R5 changes vs R4: REGISTER-STAGED pipelines (AITER-style), LDS single-buffered.
//  R4's LDS-dbuf failed because __syncthreads emits s_waitcnt vmcnt(0) which
//  drains global_load_lds prefetches (they mutate LDS). Plain VGPR-dest loads
//  are NOT drained at barriers — they wait only at first use. New K-loop:
//    r = load(kt=0)
//    for kt: { ds_write(r); barrier; r = load(kt+1); compute(LDS); barrier }
//  The vmcnt wait for r lands at ds_write — after a full compute phase of
//  cover. Exposed cost/iter: ds_write (~100cyc) + lgkm barrier drain, not
//  ~900cyc of load latency. LDS back to 32KB in both kernels.

typedef __attribute__((ext_vector_type(8))) short short8;   // 8 x bf16 (A/B frag)
typedef __attribute__((ext_vector_type(4))) short bfs4;     // 4 x bf16 packed
typedef __attribute__((ext_vector_type(4))) float f32x4;    // C/D frag
typedef __attribute__((ext_vector_type(4))) int   i32x4;    // 16B staging chunk

__device__ __forceinline__ unsigned short f2bf(float f) {
  union { float f; unsigned int u; } v; v.f = f;
  unsigned int u = v.u;
  return (unsigned short)((u + 0x7fffu + ((u >> 16) & 1u)) >> 16); // RNE
}

__device__ __forceinline__ unsigned int pk_bf16(float a, float b) {
  union { __hip_bfloat162 h; unsigned int u; } cv;
  cv.h = __float22bfloat162_rn(make_float2(a, b));   // v_cvt_pk_bf16_f32
  return cv.u;
}

// ---------------------------------------------------------------- convert x
__global__ __launch_bounds__(256) void k_convert_x(const float* __restrict__ x,
                                                   unsigned short* __restrict__ xb) {
  int g = blockIdx.x * 256 + threadIdx.x;      // 1M threads, 8 elems each
  const float4* xp = (const float4*)x + (size_t)g * 2;
  float4 a = xp[0], b = xp[1];
  short8 o;
  o[0] = (short)f2bf(a.x); o[1] = (short)f2bf(a.y);
  o[2] = (short)f2bf(a.z); o[3] = (short)f2bf(a.w);
  o[4] = (short)f2bf(b.x); o[5] = (short)f2bf(b.y);
  o[6] = (short)f2bf(b.z); o[7] = (short)f2bf(b.w);
  *(short8*)(xb + (size_t)g * 8) = o;
}

// ------------------------------------------------- convert + transpose W
// Wt[p][h][d][c] = W_p[h][c][d], bf16.
__global__ __launch_bounds__(256) void k_convert_w(const float* __restrict__ Wq,
                                                   const float* __restrict__ Wk,
                                                   const float* __restrict__ Wv,
                                                   unsigned short* __restrict__ Wt) {
  int g = blockIdx.x * 256 + threadIdx.x;      // 3*16*128*64 = 393216
  int d  = g & 63;
  int cb = (g >> 6) & 127;
  int h  = (g >> 13) & 15;
  int p  = g >> 17;
  const float* W = (p == 0) ? Wq : (p == 1) ? Wk : Wv;
  const float* src = W + ((size_t)h * 1024 + cb * 8) * 64 + d;
  short8 o;
#pragma unroll
  for (int j = 0; j < 8; ++j) o[j] = (short)f2bf(src[(size_t)j * 64]);
  *(short8*)(Wt + (((size_t)p * 16 + h) * 64 + d) * 1024 + cb * 8) = o;
}

// ---------------------------------------------------------------- QKV GEMM
// C[m][n] = sum_c A[m][c] * B[n][c]; A,B row-major [rows][1024] bf16.
// p=0: A=xb, B=Wt_q -> Qb[b][h][t][d];  p=1: -> Kb
// p=2: A=Wt_v, B=xb -> Vt[b][h][d][t]
// XCD swizzle: the 8 blocks sharing an xb tile get the same (bid&7) -> XCD.
// Register-staged pipeline, single 32KB LDS buffer, 2 barriers/iter but the
// global loads live in VGPRs across both barriers (no vmcnt drain).
__global__ __launch_bounds__(256) void k_proj(const unsigned short* __restrict__ xb,
                                              const unsigned short* __restrict__ Wt,
                                              unsigned short* __restrict__ Qb,
                                              unsigned short* __restrict__ Kb,
                                              unsigned short* __restrict__ Vt) {
  __shared__ alignas(16) unsigned short As[8192];   // 128x64 bf16, frag-major
  __shared__ alignas(16) unsigned short Bs[8192];
  const int p   = blockIdx.y;
  const int bx  = blockIdx.x;
  const int tid = threadIdx.x;
  const int lane = tid & 63, w = tid >> 6;
  const int ln = lane & 15, quad = lane >> 4;
  const int wm = w >> 1, wn = w & 1;

  const unsigned short* Abase;
  const unsigned short* Bbase;
  int m0, n0;
  const int c = bx & 7, j = bx >> 3;          // c = XCD id
  if (p < 2) {
    Abase = xb; Bbase = Wt + (size_t)p * 1048576;
    m0 = ((j >> 3) * 8 + c) * 128;            // xb m-tile pinned to XCD c
    n0 = (j & 7) * 128;
  } else {
    Abase = Wt + (size_t)2 * 1048576; Bbase = xb;
    n0 = ((j >> 3) * 8 + c) * 128;            // xb n-tile pinned to XCD c
    m0 = (j & 7) * 128;
  }

  i32x4 ra[4], rb[4];                          // staged tile kt(+1) in VGPRs
  auto ld = [&](int kt) {
    const int c0 = kt * 64;
#pragma unroll
    for (int i = 0; i < 4; ++i) {
      int idx = i * 256 + tid;                 // chunk = ikk*512 + imt*64 + iq*16 + iln
      int iln = idx & 15, iq = (idx >> 4) & 3, imt = (idx >> 6) & 7, ikk = (idx >> 9) & 1;
      int row = imt * 16 + iln;
      int col = c0 + ikk * 32 + iq * 8;
      ra[i] = *(const i32x4*)(Abase + (size_t)(m0 + row) * 1024 + col);
      rb[i] = *(const i32x4*)(Bbase + (size_t)(n0 + row) * 1024 + col);
    }
  };

  f32x4 acc[4][4];
#pragma unroll
  for (int i = 0; i < 4; ++i)
#pragma unroll
    for (int jj = 0; jj < 4; ++jj) acc[i][jj] = (f32x4){0.f, 0.f, 0.f, 0.f};

  ld(0);
  for (int kt = 0; kt < 16; ++kt) {
    // publish tile kt (vmcnt wait for ra/rb lands HERE, covered by prior compute)
#pragma unroll
    for (int i = 0; i < 4; ++i) {
      *(i32x4*)((char*)As + (size_t)(i * 256 + tid) * 16) = ra[i];
      *(i32x4*)((char*)Bs + (size_t)(i * 256 + tid) * 16) = rb[i];
    }
    __syncthreads();                           // lgkm drain only (no LDS-dest vmem)
    if (kt < 15) ld(kt + 1);                   // fire-and-forget into VGPRs

#pragma unroll
    for (int kk = 0; kk < 2; ++kk) {           // per-kk frags: caps reg liveness
      short8 af[4], bfr[4];
#pragma unroll
      for (int t4 = 0; t4 < 4; ++t4) {
        af[t4]  = *(const short8*)&As[(size_t)((((kk * 8 + wm * 4 + t4) * 4 + quad) * 16 + ln)) * 8];
        bfr[t4] = *(const short8*)&Bs[(size_t)((((kk * 8 + wn * 4 + t4) * 4 + quad) * 16 + ln)) * 8];
      }
#pragma unroll
      for (int mt = 0; mt < 4; ++mt)
#pragma unroll
        for (int nt = 0; nt < 4; ++nt)
          acc[mt][nt] = __builtin_amdgcn_mfma_f32_16x16x32_bf16(
              af[mt], bfr[nt], acc[mt][nt], 0, 0, 0);
    }
    __syncthreads();                           // readers done before next overwrite
  }

  unsigned short* outp = (p == 0) ? Qb : (p == 1) ? Kb : Vt;
#pragma unroll
  for (int mt = 0; mt < 4; ++mt)
#pragma unroll
    for (int nt = 0; nt < 4; ++nt)
#pragma unroll
      for (int r = 0; r < 4; ++r) {
        int m = m0 + (wm * 4 + mt) * 16 + quad * 4 + r;
        int n = n0 + (wn * 4 + nt) * 16 + ln;
        size_t addr;
        if (p < 2) {
          // [b][h][t][d]: m = b*1024+t, n = h*64+d
          addr = ((size_t)(m >> 10) * 16 + (n >> 6)) * 65536 + (size_t)(m & 1023) * 64 + (n & 63);
        } else {
          // Vt [b][h][d][t]: m = h*64+d, n = b*1024+t
          addr = ((size_t)(n >> 10) * 1024 + m) * 1024 + (n & 1023);
        }
        outp[addr] = f2bf(acc[mt][nt][r]);
      }
}

// ----------------------------------------------------------- flash attention
// 1-D grid, 1024 blocks. bid&127 = bh -> XCD = bh%8: all q-blocks of one
// (b,h) share one XCD's L2. qb = 7-(bid>>7): heavy blocks first.
// Block = 128 queries (4 waves x 2 q-tiles of 16). 64 keys per iteration.
// St = K*Q^T (softmax rows per-lane); fixed-max softmax (M=16, shift-exact);
// O^T = V^T*P^T; P crosses C->B layout via per-wave LDS (Ps is wave-private,
// needs no barrier). K/V register-staged, single 16KB LDS buffers.
__global__ __launch_bounds__(256) void k_attn(const unsigned short* __restrict__ Qb,
                                              const unsigned short* __restrict__ Kb,
                                              const unsigned short* __restrict__ Vt,
                                              float* __restrict__ out) {
  __shared__ alignas(16) unsigned short Ks[4096];      // 64s x 64d frag-major
  __shared__ alignas(16) unsigned short Vs[4096];      // 64d x 64s frag-major
  __shared__ alignas(16) unsigned short Ps[8192];      // 4 waves x 2 qt x 16q x 64s
  const int bid = blockIdx.x;
  const int qb = 7 - (bid >> 7);
  const int bh = bid & 127;
  const int b = bh >> 4, h = bh & 15;
  const int tid = threadIdx.x, lane = tid & 63, w = tid >> 6;
  const int ln = lane & 15, quad = lane >> 4;

  i32x4 rk[2], rv[2];
  auto ldkv = [&](int kt) {
    const int s0 = kt * 64;
#pragma unroll
    for (int i = 0; i < 2; ++i) {
      int idx = i * 256 + tid;               // chunk = it*128 + ikk*64 + iq*16 + iln
      int iln = idx & 15, iq = (idx >> 4) & 3, ikk = (idx >> 6) & 1, it = (idx >> 7) & 3;
      rk[i] = *(const i32x4*)(Kb + ((size_t)bh * 1024 + s0 + it * 16 + iln) * 64 + ikk * 32 + iq * 8);
      rv[i] = *(const i32x4*)(Vt + ((size_t)bh * 64 + it * 16 + iln) * 1024 + s0 + ikk * 32 + iq * 8);
    }
  };

  // Q B-frags for both q-tiles: lane n=q holds Q[q][kk*32+quad*8 .. +7]
  short8 qf[2][2];
#pragma unroll
  for (int qt = 0; qt < 2; ++qt) {
    const int q = qb * 128 + qt * 64 + w * 16 + ln;
#pragma unroll
    for (int kk = 0; kk < 2; ++kk)
      qf[qt][kk] = *(const short8*)(Qb + ((size_t)bh * 1024 + q) * 64 + kk * 32 + quad * 8);
  }

  f32x4 o[2][4];
#pragma unroll
  for (int qt = 0; qt < 2; ++qt)
#pragma unroll
    for (int dt = 0; dt < 4; ++dt) o[qt][dt] = (f32x4){0.f, 0.f, 0.f, 0.f};
  float l_i[2] = {0.f, 0.f};
  const float sc = 0.18033688011112042f;  // log2(e) / sqrt(64)
  const float FM = 16.0f;                 // fixed log2-domain max; |sc*st| << 16

  const int ktmax = 2 * qb + 1;
  ldkv(0);

  for (int kt = 0; kt <= ktmax; ++kt) {
    const int s0 = kt * 64;
    // publish K/V tile kt (vmcnt wait covered by previous iteration's compute)
#pragma unroll
    for (int i = 0; i < 2; ++i) {
      *(i32x4*)((char*)Ks + (size_t)(i * 256 + tid) * 16) = rk[i];
      *(i32x4*)((char*)Vs + (size_t)(i * 256 + tid) * 16) = rv[i];
    }
    __syncthreads();
    if (kt < ktmax) ldkv(kt + 1);            // fire-and-forget into VGPRs

    // QK phase: St[qt][s][q] = sum_d K[s][d] Q[q][d], kf shared across qt
    f32x4 st[2][4];
#pragma unroll
    for (int s = 0; s < 4; ++s) {
      st[0][s] = (f32x4){0.f, 0.f, 0.f, 0.f};
      st[1][s] = (f32x4){0.f, 0.f, 0.f, 0.f};
#pragma unroll
      for (int kk = 0; kk < 2; ++kk) {
        short8 kf = *(const short8*)&Ks[(size_t)(((s * 2 + kk) * 4 + quad) * 16 + ln) * 8];
        st[0][s] = __builtin_amdgcn_mfma_f32_16x16x32_bf16(kf, qf[0][kk], st[0][s], 0, 0, 0);
        st[1][s] = __builtin_amdgcn_mfma_f32_16x16x32_bf16(kf, qf[1][kk], st[1][s], 0, 0, 0);
      }
    }

    // softmax (fixed max) + P->LDS, per qt
#pragma unroll
    for (int qt = 0; qt < 2; ++qt) {
      const int q = qb * 128 + qt * 64 + w * 16 + ln;
      const bool masked = (kt >= 2 * qb + qt);   // diag tile (or fully-beyond)
      float pv[4][4];
      float rs = 0.f;
#pragma unroll
      for (int s = 0; s < 4; ++s)
#pragma unroll
        for (int r = 0; r < 4; ++r) {
          float v = fmaf(st[qt][s][r], sc, -FM);
          if (masked) {
            int sidx = s0 + s * 16 + quad * 4 + r;
            if (sidx > q) v = -1.0e30f;
          }
          float e = __builtin_amdgcn_exp2f(v);
          pv[s][r] = e;
          rs += e;
        }
      rs += __shfl_xor(rs, 16);
      rs += __shfl_xor(rs, 32);
      l_i[qt] += rs;

      unsigned short* Pq = Ps + (w * 2 + qt) * 1024;
#pragma unroll
      for (int s = 0; s < 4; ++s) {
        union { bfs4 v; unsigned int u[2]; } pk;
        pk.u[0] = pk_bf16(pv[s][0], pv[s][1]);
        pk.u[1] = pk_bf16(pv[s][2], pv[s][3]);
        *(bfs4*)&Pq[(s * 2 + (quad >> 1)) * 128 + ln * 8 + (quad & 1) * 4] = pk.v;
      }
    }

    // PV phase: O^T += V^T * P^T, vf shared across qt
#pragma unroll
    for (int kk = 0; kk < 2; ++kk) {
      short8 pf0 = *(const short8*)&Ps[(size_t)(w * 2 + 0) * 1024 + (size_t)((kk * 4 + quad) * 16 + ln) * 8];
      short8 pf1 = *(const short8*)&Ps[(size_t)(w * 2 + 1) * 1024 + (size_t)((kk * 4 + quad) * 16 + ln) * 8];
#pragma unroll
      for (int dt = 0; dt < 4; ++dt) {
        short8 vf = *(const short8*)&Vs[(size_t)(((dt * 2 + kk) * 4 + quad) * 16 + ln) * 8];
        o[0][dt] = __builtin_amdgcn_mfma_f32_16x16x32_bf16(vf, pf0, o[0][dt], 0, 0, 0);
        o[1][dt] = __builtin_amdgcn_mfma_f32_16x16x32_bf16(vf, pf1, o[1][dt], 0, 0, 0);
      }
    }

    __syncthreads();   // all waves done reading Ks/Vs before next overwrite
  }

#pragma unroll
  for (int qt = 0; qt < 2; ++qt) {
    const int q = qb * 128 + qt * 64 + w * 16 + ln;
    const float rl = 1.0f / l_i[qt];
#pragma unroll
    for (int dt = 0; dt < 4; ++dt) {
      float4 ov;
      ov.x = o[qt][dt][0] * rl; ov.y = o[qt][dt][1] * rl;
      ov.z = o[qt][dt][2] * rl; ov.w = o[qt][dt][3] * rl;
      *(float4*)(out + ((size_t)b * 1024 + q) * 1024 + h * 64 + dt * 16 + quad * 4) = ov;
    }
  }
}

// ---------------------------------------------------------------- launcher
extern "C" void kernel_launch(void* const* d_in, const int* in_sizes, int n_in,
                              void* d_out, int out_size, void* d_ws, size_t ws_size,
                              hipStream_t stream) {
  const float* x  = (const float*)d_in[0];
  const float* Wq = (const float*)d_in[1];
  const float* Wk = (const float*)d_in[2];
  const float* Wv = (const float*)d_in[3];
  float* out = (float*)d_out;

  unsigned short* ws = (unsigned short*)d_ws;
  unsigned short* xb = ws;                      // 8M bf16  (16 MB)
  unsigned short* Wt = ws + 8388608;            // 3M bf16  (6 MB), [p][h][d][c]
  unsigned short* Qb = ws + 11534336;           // 8M bf16  [b][h][t][d]
  unsigned short* Kb = ws + 19922944;           // 8M bf16  [b][h][t][d]
  unsigned short* Vt = ws + 28311552;           // 8M bf16  [b][h][d][t]
  // total 73,400,320 bytes of d_ws

  hipLaunchKernelGGL(k_convert_x, dim3(4096), dim3(256), 0, stream, x, xb);
  hipLaunchKernelGGL(k_convert_w, dim3(1536), dim3(256), 0, stream, Wq, Wk, Wv, Wt);
  hipLaunchKernelGGL(k_proj, dim3(512, 3), dim3(256), 0, stream, xb, Wt, Qb, Kb, Vt);
  hipLaunchKernelGGL(k_attn, dim3(1024), dim3(256), 0, stream, Qb, Kb, Vt, out);
}